// Round 12
// baseline (972.647 us; speedup 1.0000x reference)
//
#include <hip/hip_runtime.h>

// ---------------- problem constants (match reference) ----------------
#define Zl      384
#define MBr     46
#define NBc     68
#define DEG     7
#define K_INFO  8448
#define N_TX    25344
#define N_LDPC  (NBc * Zl)        // 26112
#define M_CHK   (MBr * Zl)        // 17664
#define E_EDGE  (MBr * DEG * Zl)  // 123648
#define BATCH   128
#define NUM_ITER 20
#define LLR_MAXF 20.0f
#define BCAP    32

// NUMERICS CONTRACT (validated rounds 7-11, absmax 0.0625 vs 0.45):
//  - pure f32 end to end
//  - VN sum: accumulator starts at lch[v], then messages added in
//    ASCENDING edge-id order. DO NOT REORDER (other orders: 1.4-2.0).
//  - CN: two-min with strict < (first-argmin), sign via parity mask.
//  - CN state compression is EXACT (messages are +-min1/+-min2).
// Batch elements are independent -> batch partitioning is order-safe.
//
// PERF MODEL (R9-R11): time ~ beyond-L2 traffic / ~4 TB/s. Batch-sliced
// XCD pinning (R11) alone was neutral: per-XCD reuse set (state 3.4MB or
// x 1.6MB) is evicted by co-flowing streams (lch/x/state ~3-5MB) before
// its ~7 touches complete. R12: mark single-touch streams NON-TEMPORAL
// (evict-first) so reused lines stay L2-resident:
//   CN: old state/meta NT (read once)   | protects x-gather + state-w
//   VN: lch NT (read once)              | protects state/meta + x-w
// Cross-dispatch retention relies on same-XCD pinning (bid%8) and
// agent-scope (no L2 invalidate) dispatch boundaries.

// meta bits: [2:0]=amin, [9:3]=nm (neg mask), [10]=stot (parity)

typedef float  f4v __attribute__((ext_vector_type(4)));
typedef unsigned short u4v __attribute__((ext_vector_type(4)));

// ---------------------------------------------------------------------
// prep: lch[(2Z+n)*128 + b] = -clip(llr[b*N_TX + n])   (tiled transpose)
// ---------------------------------------------------------------------
__global__ void prep_kernel(const float* __restrict__ llr, float* __restrict__ lch) {
    __shared__ float tile[32][33];
    const int n0 = blockIdx.x * 32, b0 = blockIdx.y * 32;
    const int tx = threadIdx.x, ty = threadIdx.y;
#pragma unroll
    for (int j = 0; j < 4; ++j) {
        float v = llr[(b0 + ty + 8 * j) * N_TX + n0 + tx];
        v = fminf(fmaxf(v, -LLR_MAXF), LLR_MAXF);
        tile[ty + 8 * j][tx] = -v;          // [b_local][n_local]
    }
    __syncthreads();
#pragma unroll
    for (int j = 0; j < 4; ++j) {
        lch[(2 * Zl + n0 + ty + 8 * j) * BATCH + b0 + tx] = tile[tx][ty + 8 * j];
    }
}

// ---------------------------------------------------------------------
// adjacency build, deterministic ascending base-edge order.
// badj[c*BCAP + slot] = sh | (d<<10) | (r<<13)   (sh<512, d<8, r<64)
// ---------------------------------------------------------------------
__global__ void base_build_kernel(const int* __restrict__ col,
                                  int* __restrict__ bcount, int* __restrict__ badj) {
    __shared__ int sc[MBr * DEG];
    __shared__ int ssh[MBr * DEG];
    const int t = threadIdx.x;
    if (t < MBr * DEG) {
        const int v0 = col[t * Zl];         // col[be*Z] = c*Z + shift
        const int c  = v0 / Zl;
        sc[t]  = c;
        ssh[t] = v0 - c * Zl;
    }
    if (t < NBc) bcount[t] = 0;
    __syncthreads();
    if (t < MBr * DEG) {
        const int c = sc[t];
        int slot = 0;
        for (int u = 0; u < t; ++u) slot += (sc[u] == c) ? 1 : 0;
        const int r = t / DEG, d = t - r * DEG;
        if (slot < BCAP) badj[c * BCAP + slot] = ssh[t] | (d << 10) | (r << 13);
        atomicAdd(&bcount[c], 1);           // order-independent (count only)
    }
}

// ---------------------------------------------------------------------
// CN update, batch-sliced: blockIdx%8 = batch-group (quads 4g..4g+3),
// blockIdx/8 = tile of 64 check nodes. 4 lanes per node, float4 each.
// Old state/meta loads are NON-TEMPORAL (single touch).
// ---------------------------------------------------------------------
template <bool FIRST>
__global__ void cn_kernel(const float* __restrict__ x,
                          float* __restrict__ state_f2,
                          unsigned short* __restrict__ meta,
                          const int* __restrict__ col) {
    const int qg   = blockIdx.x & 7;          // batch group -> XCD
    const int tile = blockIdx.x >> 3;
    const int nl   = threadIdx.x >> 2;        // node within tile (0..63)
    const int ql   = threadIdx.x & 3;
    const int q    = qg * 4 + ql;             // float4 quad (0..31)
    const int cn   = tile * 64 + nl;
    const int r    = cn / Zl;
    const int i    = cn - r * Zl;
    const int ebase = r * DEG * Zl + i;

    float omin1[4], omin2[4];
    int oamin[4]; unsigned onm[4], ostot[4];
    if (!FIRST) {
        const f4v sA = __builtin_nontemporal_load(((const f4v*)state_f2) + cn * 64 + 2 * q);
        const f4v sB = __builtin_nontemporal_load(((const f4v*)state_f2) + cn * 64 + 2 * q + 1);
        omin1[0] = sA[0]; omin2[0] = sA[1]; omin1[1] = sA[2]; omin2[1] = sA[3];
        omin1[2] = sB[0]; omin2[2] = sB[1]; omin1[3] = sB[2]; omin2[3] = sB[3];
        const u4v mt = __builtin_nontemporal_load(((const u4v*)meta) + cn * 32 + q);
        const unsigned m4[4] = {mt[0], mt[1], mt[2], mt[3]};
#pragma unroll
        for (int c = 0; c < 4; ++c) {
            oamin[c] = m4[c] & 7u;
            onm[c]   = (m4[c] >> 3) & 0x7Fu;
            ostot[c] = (m4[c] >> 10) & 1u;
        }
    }

    float min1[4] = {1e30f, 1e30f, 1e30f, 1e30f};
    float min2[4] = {1e30f, 1e30f, 1e30f, 1e30f};
    int   amin[4] = {0, 0, 0, 0};
    unsigned nm[4] = {0u, 0u, 0u, 0u};

#pragma unroll
    for (int d = 0; d < DEG; ++d) {
        const int e = ebase + d * Zl;
        const int v = col[e];
        const f4v xv = ((const f4v*)x)[v * 32 + q];   // reused x7 per XCD: keep cached
        float t[4] = {xv[0], xv[1], xv[2], xv[3]};
        if (!FIRST) {
#pragma unroll
            for (int c = 0; c < 4; ++c) {
                const float omag = (d == oamin[c]) ? omin2[c] : omin1[c];
                const float mold = (ostot[c] ^ ((onm[c] >> d) & 1u)) ? -omag : omag;
                t[c] -= mold;
            }
        }
#pragma unroll
        for (int c = 0; c < 4; ++c) {
            const float mag = fabsf(t[c]);
            nm[c] |= (t[c] < 0.f ? 1u : 0u) << d;
            if (mag < min1[c]) { min2[c] = min1[c]; min1[c] = mag; amin[c] = d; }
            else if (mag < min2[c]) { min2[c] = mag; }
        }
    }

    f4v oA, oB;
    oA[0] = min1[0]; oA[1] = min2[0]; oA[2] = min1[1]; oA[3] = min2[1];
    oB[0] = min1[2]; oB[1] = min2[2]; oB[2] = min1[3]; oB[3] = min2[3];
    ((f4v*)state_f2)[cn * 64 + 2 * q]     = oA;   // normal: VN re-reads on same XCD
    ((f4v*)state_f2)[cn * 64 + 2 * q + 1] = oB;
    u4v mo;
    unsigned mv[4];
#pragma unroll
    for (int c = 0; c < 4; ++c)
        mv[c] = (unsigned)amin[c] | (nm[c] << 3) | ((unsigned)(__popc(nm[c]) & 1) << 10);
    mo[0] = (unsigned short)mv[0]; mo[1] = (unsigned short)mv[1];
    mo[2] = (unsigned short)mv[2]; mo[3] = (unsigned short)mv[3];
    ((u4v*)meta)[cn * 32 + q] = mo;
}

// ---------------------------------------------------------------------
// VN update (LCH-FIRST), batch-sliced like cn_kernel.
// lch load is NON-TEMPORAL (single touch); state/meta loads cached
// (each line touched ~7x within the XCD).
// ---------------------------------------------------------------------
__global__ void vn_kernel(const float* __restrict__ lch,
                          const float* __restrict__ state_f2,
                          const unsigned short* __restrict__ meta,
                          const int* __restrict__ bcount, const int* __restrict__ badj,
                          float* __restrict__ x) {
    const int qg   = blockIdx.x & 7;
    const int tile = blockIdx.x >> 3;
    const int nl   = threadIdx.x >> 2;
    const int ql   = threadIdx.x & 3;
    const int q    = qg * 4 + ql;
    const int v    = tile * 64 + nl;
    const int c    = v / Zl;
    const int j    = v - c * Zl;
    const int cnt  = min(bcount[c], BCAP);
    const int* bp  = badj + c * BCAP;
    const f4v l4 = __builtin_nontemporal_load(((const f4v*)lch) + v * 32 + q);
    float s0 = l4[0], s1 = l4[1], s2 = l4[2], s3 = l4[3];   // lch FIRST
    for (int k = 0; k < cnt; ++k) {
        const int pk = bp[k];
        const int sh = pk & 0x3FF;
        const int d  = (pk >> 10) & 7;
        const int r  = pk >> 13;
        int i = j - sh;
        if (i < 0) i += Zl;
        const int cn = r * Zl + i;
        const f4v sA = ((const f4v*)state_f2)[cn * 64 + 2 * q];
        const f4v sB = ((const f4v*)state_f2)[cn * 64 + 2 * q + 1];
        const u4v mt = ((const u4v*)meta)[cn * 32 + q];
        const unsigned m4[4] = {mt[0], mt[1], mt[2], mt[3]};
        const float mn1[4] = {sA[0], sA[2], sB[0], sB[2]};
        const float mn2[4] = {sA[1], sA[3], sB[1], sB[3]};
        float val[4];
#pragma unroll
        for (int cc = 0; cc < 4; ++cc) {
            const int   am  = m4[cc] & 7u;
            const unsigned nmv = (m4[cc] >> 3) & 0x7Fu;
            const unsigned st  = (m4[cc] >> 10) & 1u;
            const float mag = (d == am) ? mn2[cc] : mn1[cc];
            val[cc] = (st ^ ((nmv >> d) & 1u)) ? -mag : mag;
        }
        s0 += val[0]; s1 += val[1]; s2 += val[2]; s3 += val[3];
    }
    f4v o; o[0] = s0; o[1] = s1; o[2] = s2; o[3] = s3;
    ((f4v*)x)[v * 32 + q] = o;                 // normal: CN re-reads on same XCD
}

// ---------------------------------------------------------------------
// output: out[b*K + k] = -x[k*128 + b], k < K_INFO   (tiled transpose)
// ---------------------------------------------------------------------
__global__ void out_kernel(const float* __restrict__ x, float* __restrict__ out) {
    __shared__ float tile[32][33];
    const int k0 = blockIdx.x * 32, b0 = blockIdx.y * 32;
    const int tx = threadIdx.x, ty = threadIdx.y;
#pragma unroll
    for (int j = 0; j < 4; ++j) {
        tile[ty + 8 * j][tx] = -x[(k0 + ty + 8 * j) * BATCH + b0 + tx];
    }
    __syncthreads();
#pragma unroll
    for (int j = 0; j < 4; ++j) {
        out[(b0 + ty + 8 * j) * K_INFO + k0 + tx] = tile[tx][ty + 8 * j];
    }
}

// ---------------------------------------------------------------------
extern "C" void kernel_launch(void* const* d_in, const int* in_sizes, int n_in,
                              void* d_out, int out_size, void* d_ws, size_t ws_size,
                              hipStream_t stream) {
    const float* llr = (const float*)d_in[0];
    // d_in[1] = row (unused: row index derivable from edge-id structure)
    const int* col = (const int*)d_in[2];
    float* out = (float*)d_out;

    char* ws = (char*)d_ws;
    float* lch   = (float*)ws;                                   // 13,369,344 B
    float* x     = lch + (size_t)N_LDPC * BATCH;                 // 13,369,344 B
    float* state = x + (size_t)N_LDPC * BATCH;                   // 18,087,936 B
    unsigned short* meta = (unsigned short*)(state + (size_t)M_CHK * BATCH * 2); // 4,521,984 B
    int* bcount = (int*)(meta + (size_t)M_CHK * BATCH);          // 68*4
    int* badj   = bcount + NBc;                                  // 68*32*4
    // total ~49.4 MB

    hipMemsetAsync(lch, 0, (size_t)(2 * Zl) * BATCH * sizeof(float), stream);
    prep_kernel<<<dim3(N_TX / 32, BATCH / 32), dim3(32, 8), 0, stream>>>(llr, lch);

    base_build_kernel<<<1, 512, 0, stream>>>(col, bcount, badj);

    // grids: (node_tiles) x 8 batch-groups; %8 -> XCD round-robin
    const int cn_grid = (M_CHK / 64) * 8;    // 276*8 = 2208
    const int vn_grid = (N_LDPC / 64) * 8;   // 408*8 = 3264

    // iteration 1: vn_sum == lch exactly (m_cv == 0)
    cn_kernel<true><<<cn_grid, 256, 0, stream>>>(lch, state, meta, col);
    vn_kernel<<<vn_grid, 256, 0, stream>>>(lch, state, meta, bcount, badj, x);

    for (int t = 1; t < NUM_ITER; ++t) {
        cn_kernel<false><<<cn_grid, 256, 0, stream>>>(x, state, meta, col);
        vn_kernel<<<vn_grid, 256, 0, stream>>>(lch, state, meta, bcount, badj, x);
    }

    out_kernel<<<dim3(K_INFO / 32, BATCH / 32), dim3(32, 8), 0, stream>>>(x, out);
}